// Round 3
// baseline (992.527 us; speedup 1.0000x reference)
//
#include <hip/hip_runtime.h>

// Correlation layer: out[b, dh*9+dw, h, w] =
//   (1/196) * sum_c in1[b,c,h,w] * in2[b,c, refl(h+dh-4), refl(w+dw-4)]
// in1,in2 = [8,196,128,224] f32 ; out = [8,81,128,224] f32
//
// v4 = v0 (empirical best: no block swizzle, two-barrier single-buffer round,
// loads issued AFTER barrier-2 so the pre-barrier vmcnt(0) drain lands a full
// compute phase after issue) with:
//   * KC 2->4: 49 rounds instead of 98 -- half the barrier/drain events, 2x
//     per-round compute to hide each round's load latency.
//   * WS=236 row stride (bank-phase spread; v3 measured conflicts 2.6e7->1.0e7).
// Swizzle REVERTED: lockstep same-line access from co-XCD blocks serialized in
// L2 and cost 45% (v2/v3). Default dispatch + L3 handles reuse.

constexpr int NB = 8, NC = 196, NH = 128, NW = 224;
constexpr int ND = 9;            // displacements per axis
constexpr int PADV = 4;
constexpr int WS = 236;          // staged row stride (floats): 232 used + 4 pad
constexpr int KC = 4;            // channels per round
constexpr int NSLOT = 56;        // w-groups of 4
constexpr int ACTIVE = ND * NSLOT;   // 504 compute threads
constexpr int TPB = 512;
constexpr int HWSZ = NH * NW;    // 28672
constexpr int NR = NC / KC;      // 49 rounds
constexpr int NBLK = NB * NH;    // 1024

constexpr int NVEC  = KC * ND * NSLOT;        // 2016 float4 staging slots
constexpr int NEDGE = KC * ND * 8;            // 288 edge scalars
constexpr int NK    = (NVEC + TPB - 1) / TPB; // 4 slots/thread

__device__ __forceinline__ int refl(int v, int n) {
    v = v < 0 ? -v : v;
    return v >= n ? 2 * n - 2 - v : v;
}

__global__ __launch_bounds__(TPB)
void corr_kernel(const float* __restrict__ in1,
                 const float* __restrict__ in2,
                 float* __restrict__ out)
{
    __shared__ __align__(16) float s_win[KC][ND][WS];   // 33,984 B

    const int tid = threadIdx.x;
    const int bh  = blockIdx.x;          // default dispatch order (no swizzle)
    const int b   = bh / NH;
    const int h   = bh - b * NH;

    // ---- staging precompute (fixed across rounds; round adds c*HWSZ) ----
    // Part A: interior vector slots: KC*ND*56 = 2016 float4 slots
    const float* gA[NK];
    int  lA[NK];
    bool vA[NK];
#pragma unroll
    for (int k = 0; k < NK; ++k) {
        int v  = tid + k * TPB;
        vA[k]  = v < NVEC;
        int vv = vA[k] ? v : 0;
        int cc = vv / (ND * NSLOT);
        int r  = vv - cc * (ND * NSLOT);
        int dh = r / NSLOT;
        int g  = r - dh * NSLOT;
        int y  = refl(h + dh - PADV, NH);
        gA[k]  = in2 + ((b * NC + cc) * NH + y) * NW + 4 * g;
        lA[k]  = (cc * ND + dh) * WS + 4 + 4 * g;
    }
    // Part B: edge scalars: e<4: s=e, x=4-e ; e>=4: s=224+e, x=226-e
    const float* gB = in2;
    int  lB = 0;
    const bool vB = tid < NEDGE;
    {
        int v  = vB ? tid : 0;
        int cc = v / (ND * 8);
        int r  = v - cc * (ND * 8);
        int dh = r / 8;
        int e  = r - dh * 8;
        int s  = e < 4 ? e : 224 + e;
        int x  = e < 4 ? 4 - e : 226 - e;
        int y  = refl(h + dh - PADV, NH);
        gB = in2 + ((b * NC + cc) * NH + y) * NW + x;
        lB = (cc * ND + dh) * WS + s;
    }

    // ---- compute-thread identity (dh-major) ----
    const int  cdh  = tid / NSLOT;          // 0..8
    const int  slot = tid - cdh * NSLOT;    // 0..55
    const int  w0   = slot * 4;
    const bool compute = tid < ACTIVE;
    const float* a1p = in1 + ((b * NC) * NH + h) * NW + w0;   // + c*HWSZ per channel

    float acc[ND][4];
#pragma unroll
    for (int d = 0; d < ND; ++d)
#pragma unroll
        for (int p = 0; p < 4; ++p) acc[d][p] = 0.f;

    const int STEP = KC * HWSZ;             // per-round channel advance (floats)

    // ---- register-buffered prefetch of round 0 ----
    float4 bufA[NK];
    float  bufB = 0.f;
#pragma unroll
    for (int k = 0; k < NK; ++k)
        if (vA[k]) bufA[k] = *(const float4*)(gA[k]);
    if (vB) bufB = gB[0];

    for (int r = 0; r < NR; ++r) {
        __syncthreads();                    // LDS free from previous round
#pragma unroll
        for (int k = 0; k < NK; ++k)
            if (vA[k]) *(float4*)&((float*)s_win)[lA[k]] = bufA[k];
        if (vB) ((float*)s_win)[lB] = bufB;
        __syncthreads();

        // issue next round's global loads NOW; the vmcnt(0) drain at the next
        // barrier lands a full compute phase (~2x longer than v0's) after issue
        if (r + 1 < NR) {
            const int off = (r + 1) * STEP;
#pragma unroll
            for (int k = 0; k < NK; ++k)
                if (vA[k]) bufA[k] = *(const float4*)(gA[k] + off);
            if (vB) bufB = gB[off];
        }

        if (compute) {
#pragma unroll
            for (int cc = 0; cc < KC; ++cc) {
                const float* wrow = &s_win[cc][cdh][w0];
                float4 wv0 = *(const float4*)(wrow);
                float4 wv1 = *(const float4*)(wrow + 4);
                float4 wv2 = *(const float4*)(wrow + 8);
                float4 a   = *(const float4*)(a1p + (r * KC + cc) * HWSZ);
                const float wn[12] = {wv0.x, wv0.y, wv0.z, wv0.w,
                                      wv1.x, wv1.y, wv1.z, wv1.w,
                                      wv2.x, wv2.y, wv2.z, wv2.w};
#pragma unroll
                for (int d = 0; d < ND; ++d) {
                    acc[d][0] += a.x * wn[d + 0];
                    acc[d][1] += a.y * wn[d + 1];
                    acc[d][2] += a.z * wn[d + 2];
                    acc[d][3] += a.w * wn[d + 3];
                }
            }
        }
    }

    if (compute) {
        const float scale = 1.0f / 196.0f;
#pragma unroll
        for (int d = 0; d < ND; ++d) {
            float4 o;
            o.x = acc[d][0] * scale;
            o.y = acc[d][1] * scale;
            o.z = acc[d][2] * scale;
            o.w = acc[d][3] * scale;
            float* op = out + (((b * (ND * ND)) + cdh * ND + d) * NH + h) * NW + w0;
            *(float4*)op = o;
        }
    }
}

extern "C" void kernel_launch(void* const* d_in, const int* in_sizes, int n_in,
                              void* d_out, int out_size, void* d_ws, size_t ws_size,
                              hipStream_t stream)
{
    const float* in1 = (const float*)d_in[0];
    const float* in2 = (const float*)d_in[1];
    float* outp = (float*)d_out;
    dim3 grid(NBLK);
    dim3 block(TPB);
    hipLaunchKernelGGL(corr_kernel, grid, block, 0, stream, in1, in2, outp);
}